// Round 1
// baseline (3058.118 us; speedup 1.0000x reference)
//
#include <hip/hip_runtime.h>
#include <hip/hip_bf16.h>

// ---------------------------------------------------------------------------
// LSTM-CRF forward on MI355X.
// Pipeline: prep (weight conv) -> embed/pack -> GEMM_in(l0 f/b) -> LSTM l0 ->
//           GEMM_in(l1 f/b) -> LSTM l1 -> emissions GEMM -> CRF.
// Sizes: B=32, T=256, V=50000, E=300, HD=256, K=64.
// ---------------------------------------------------------------------------

#define Bv 32
#define Tv 256
#define Ev 300
#define HDv 256
#define Kv 64
#define MROWS (Bv * Tv)          // 8192
#define K0PAD 320                // 301 padded to mult of 32
#define K1 512
#define GATES 1024               // 4*HD

typedef __bf16 v8bf __attribute__((ext_vector_type(8)));
typedef float  v4f  __attribute__((ext_vector_type(4)));

__device__ __forceinline__ unsigned short f2bf(float f) {
    unsigned u = __float_as_uint(f);
    unsigned r = (u + 0x7fffu + ((u >> 16) & 1u)) >> 16;
    return (unsigned short)r;
}
__device__ __forceinline__ float bflo(unsigned u) { return __uint_as_float(u << 16); }
__device__ __forceinline__ float bfhi(unsigned u) { return __uint_as_float(u & 0xffff0000u); }
__device__ __forceinline__ float sigf(float x) { return 1.0f / (1.0f + __expf(-x)); }
__device__ __forceinline__ float tanhf2(float x) {
    x = fminf(15.f, fmaxf(-15.f, x));
    float e = __expf(2.f * x);
    return (e - 1.f) / (e + 1.f);
}

// ---------------- prep kernels ----------------

// z=0: Wih_l0f [1024,301]->[1024,320]  z=1: Wih_l0b
// z=2: Wih_l1f [1024,512]             z=3: Wih_l1b   z=4: out_w [64,512]
__global__ void conv_weights(const float* w0f, const float* w0b,
                             const float* w1f, const float* w1b,
                             const float* outw,
                             unsigned short* dW0, unsigned short* dW1,
                             unsigned short* dOW) {
    int z = blockIdx.z;
    const float* src; unsigned short* dst; int rows, kin, kout;
    if (z == 0)      { src = w0f;  dst = dW0;               rows = 1024; kin = 301; kout = K0PAD; }
    else if (z == 1) { src = w0b;  dst = dW0 + 1024 * K0PAD; rows = 1024; kin = 301; kout = K0PAD; }
    else if (z == 2) { src = w1f;  dst = dW1;               rows = 1024; kin = 512; kout = 512; }
    else if (z == 3) { src = w1b;  dst = dW1 + 1024 * 512;  rows = 1024; kin = 512; kout = 512; }
    else             { src = outw; dst = dOW;               rows = 64;   kin = 512; kout = 512; }
    int idx = blockIdx.x * 256 + threadIdx.x;
    if (idx >= rows * kout) return;
    int j = idx / kout, k = idx - j * kout;
    dst[idx] = (k < kin) ? f2bf(src[j * kin + k]) : (unsigned short)0;
}

// Whh [1024,256] fp32 -> packed-transposed bf16 pairs:
// WQ dword layout: ((kb*1024 + j)*4 + q) holds (bf16 W[j][8kb+2q+1] << 16) | bf16 W[j][8kb+2q]
__global__ void pack_whh(const float* h0f, const float* h0b,
                         const float* h1f, const float* h1b, unsigned int* WQ) {
    int z = blockIdx.z;
    const float* src = (z == 0) ? h0f : (z == 1) ? h0b : (z == 2) ? h1f : h1b;
    unsigned int* dst = WQ + (size_t)z * 131072;
    int idx = blockIdx.x * 256 + threadIdx.x;      // 0..131071
    int j = idx & 1023;
    int kp = idx >> 10;                            // 0..127 (k-pair)
    int kb = kp >> 2, q = kp & 3;
    unsigned lo = f2bf(src[j * 256 + 2 * kp]);
    unsigned hi = f2bf(src[j * 256 + 2 * kp + 1]);
    dst[((kb << 10) + j) * 4 + q] = lo | (hi << 16);
}

__global__ void bias_sum(const float* a0, const float* b0, const float* a1, const float* b1,
                         const float* a2, const float* b2, const float* a3, const float* b3,
                         float* bias) {
    int idx = blockIdx.x * 256 + threadIdx.x;      // 0..4095
    int dl = idx >> 10, j = idx & 1023;
    const float* A = (dl == 0) ? a0 : (dl == 1) ? a1 : (dl == 2) ? a2 : a3;
    const float* B = (dl == 0) ? b0 : (dl == 1) ? b1 : (dl == 2) ? b2 : b3;
    bias[idx] = A[j] + B[j];
}

__global__ void calc_len(const int* x, int* lengths) {
    __shared__ int cnt;
    if (threadIdx.x == 0) cnt = 0;
    __syncthreads();
    if (x[blockIdx.x * Tv + threadIdx.x] > 0) atomicAdd(&cnt, 1);
    __syncthreads();
    if (threadIdx.x == 0) lengths[blockIdx.x] = cnt;
}

// X0 row = [embed[tok](300) | f(1) | zeros(19)] as bf16
__global__ void embed_pack(const int* __restrict__ x, const float* __restrict__ f,
                           const float* __restrict__ embed, unsigned short* __restrict__ X0) {
    int row = blockIdx.x;
    int tok = x[row];
    float fv = f[row];
    const float* e = embed + (size_t)tok * Ev;
    for (int k = threadIdx.x; k < K0PAD; k += 64) {
        float v = (k < Ev) ? e[k] : ((k == Ev) ? fv : 0.f);
        X0[(size_t)row * K0PAD + k] = f2bf(v);
    }
}

// ---------------- MFMA GEMM: C[M,N] = X[M,K] @ W[N,K]^T + bias[N] ----------
// one wave per 32x32 tile, direct global loads (L2-served)
__global__ __launch_bounds__(64) void mfma_gemm(
    const unsigned short* __restrict__ X, int ldx,
    const unsigned short* __restrict__ W, int ldw,
    const float* __restrict__ bias, float* __restrict__ C, int ldc, int K) {
    int lane = threadIdx.x;
    int m0 = blockIdx.x * 32, n0 = blockIdx.y * 32;
    int r = lane & 15, q = lane >> 4;
    const unsigned short* xa = X + (size_t)(m0 + r) * ldx + q * 8;
    const unsigned short* xb = xa + (size_t)16 * ldx;
    const unsigned short* wa = W + (size_t)(n0 + r) * ldw + q * 8;
    const unsigned short* wb = wa + (size_t)16 * ldw;
    v4f acc00 = {0.f, 0.f, 0.f, 0.f};
    v4f acc01 = acc00, acc10 = acc00, acc11 = acc00;
#pragma unroll 4
    for (int k = 0; k < K; k += 32) {
        v8bf a0 = *(const v8bf*)(xa + k);
        v8bf a1 = *(const v8bf*)(xb + k);
        v8bf b0 = *(const v8bf*)(wa + k);
        v8bf b1 = *(const v8bf*)(wb + k);
        acc00 = __builtin_amdgcn_mfma_f32_16x16x32_bf16(a0, b0, acc00, 0, 0, 0);
        acc01 = __builtin_amdgcn_mfma_f32_16x16x32_bf16(a0, b1, acc01, 0, 0, 0);
        acc10 = __builtin_amdgcn_mfma_f32_16x16x32_bf16(a1, b0, acc10, 0, 0, 0);
        acc11 = __builtin_amdgcn_mfma_f32_16x16x32_bf16(a1, b1, acc11, 0, 0, 0);
    }
    int col = n0 + r;
    float bv0 = bias[col], bv1 = bias[col + 16];
#pragma unroll
    for (int i = 0; i < 4; ++i) {
        int row = m0 + q * 4 + i;
        C[(size_t)row * ldc + col]             = acc00[i] + bv0;
        C[(size_t)row * ldc + col + 16]        = acc01[i] + bv1;
        C[(size_t)(row + 16) * ldc + col]      = acc10[i] + bv0;
        C[(size_t)(row + 16) * ldc + col + 16] = acc11[i] + bv1;
    }
}

// ---------------- LSTM recurrence ----------------
// grid (32 batches, 2 dirs), block 1024. Gin dir-major [2][8192][1024] fp32
// (input GEMM + combined bias). WQ: this layer's packed Whh (dir-major).
// Hout bf16 [8192][512], this dir writes its 256-half. Masked steps skipped
// (mask is contiguous prefix => identical semantics to reference).
__global__ __launch_bounds__(1024) void lstm_kernel(
    const float* __restrict__ Gin, const unsigned int* __restrict__ WQ,
    unsigned short* __restrict__ Hout, const int* __restrict__ lengths) {
    int b = blockIdx.x, dir = blockIdx.y;
    int j = threadIdx.x;
    int len = lengths[b];
    const float* gin = Gin + (size_t)dir * MROWS * GATES + (size_t)b * Tv * GATES;
    const uint4* wq = (const uint4*)(WQ + (size_t)dir * 131072);
    __shared__ __align__(16) float hs[HDv];
    __shared__ float cs[HDv];
    __shared__ float gs[GATES];
    if (j < HDv) { hs[j] = 0.f; cs[j] = 0.f; }
    __syncthreads();
    const uint4* wp = wq + j;
    for (int s = 0; s < len; ++s) {
        int t = dir ? (len - 1 - s) : s;
        float g = gin[(size_t)t * GATES + j];
#pragma unroll 8
        for (int kb = 0; kb < 32; ++kb) {
            uint4 u = wp[kb << 10];
            float4 hA = *(const float4*)&hs[kb * 8];
            float4 hB = *(const float4*)&hs[kb * 8 + 4];
            g = fmaf(hA.x, bflo(u.x), g); g = fmaf(hA.y, bfhi(u.x), g);
            g = fmaf(hA.z, bflo(u.y), g); g = fmaf(hA.w, bfhi(u.y), g);
            g = fmaf(hB.x, bflo(u.z), g); g = fmaf(hB.y, bfhi(u.z), g);
            g = fmaf(hB.z, bflo(u.w), g); g = fmaf(hB.w, bfhi(u.w), g);
        }
        gs[j] = g;
        __syncthreads();
        if (j < HDv) {
            float ig = sigf(gs[j]);
            float fg = sigf(gs[HDv + j]);
            float gg = tanhf2(gs[2 * HDv + j]);
            float og = sigf(gs[3 * HDv + j]);
            float c = fg * cs[j] + ig * gg;
            float h = og * tanhf2(c);
            cs[j] = c; hs[j] = h;
            Hout[((size_t)(b * Tv + t)) * 512 + dir * HDv + j] = f2bf(h);
        }
        __syncthreads();
    }
}

// ---------------- CRF ----------------
// grid 32 (batch), block 64 (one wave). Y fp32 [8192][64] valid rows only.
__global__ __launch_bounds__(64) void crf_kernel(
    const float* __restrict__ Y, const float* __restrict__ trans,
    const int* __restrict__ y0, const int* __restrict__ lengths,
    float* __restrict__ out) {
    int b = blockIdx.x, j = threadIdx.x;
    int len = lengths[b];
    float trj[64];
#pragma unroll
    for (int i = 0; i < 64; ++i) trj[i] = trans[j * 64 + i];
    __shared__ __align__(16) float s[64];
    s[j] = (j == 2) ? 0.f : -10000.f;
    __syncthreads();
    const float* yb = Y + (size_t)b * Tv * Kv;
    for (int t = 0; t < len; ++t) {
        float emit = yb[t * 64 + j];
        float m = -3.0e38f;
#pragma unroll
        for (int i = 0; i < 64; ++i) m = fmaxf(m, s[i] + trj[i]);
        float sum = 0.f;
#pragma unroll
        for (int i = 0; i < 64; ++i) sum += __expf(s[i] + trj[i] - m);
        float ns = m + __logf(sum) + emit;
        __syncthreads();
        s[j] = ns;
        __syncthreads();
    }
    float v = s[j];
    float M = v;
#pragma unroll
    for (int o = 32; o; o >>= 1) M = fmaxf(M, __shfl_xor(M, o));
    float e = __expf(v - M);
#pragma unroll
    for (int o = 32; o; o >>= 1) e += __shfl_xor(e, o);
    float Z = M + __logf(e);
    float gold = 0.f;
    for (int t = j; t < len; t += 64) {
        int yt = y0[b * Tv + t];
        int yp = (t == 0) ? 2 : y0[b * Tv + t - 1];
        gold += yb[t * 64 + yt] + trans[yt * 64 + yp];
    }
#pragma unroll
    for (int o = 32; o; o >>= 1) gold += __shfl_xor(gold, o);
    if (j == 0) out[b] = Z - gold;
}

// ---------------- host ----------------
extern "C" void kernel_launch(void* const* d_in, const int* in_sizes, int n_in,
                              void* d_out, int out_size, void* d_ws, size_t ws_size,
                              hipStream_t stream) {
    const int*   x     = (const int*)d_in[0];
    const float* f     = (const float*)d_in[1];
    const int*   y0    = (const int*)d_in[2];
    const float* embed = (const float*)d_in[3];
    const float* Wih0f = (const float*)d_in[4],  *Whh0f = (const float*)d_in[5];
    const float* bih0f = (const float*)d_in[6],  *bhh0f = (const float*)d_in[7];
    const float* Wih0b = (const float*)d_in[8],  *Whh0b = (const float*)d_in[9];
    const float* bih0b = (const float*)d_in[10], *bhh0b = (const float*)d_in[11];
    const float* Wih1f = (const float*)d_in[12], *Whh1f = (const float*)d_in[13];
    const float* bih1f = (const float*)d_in[14], *bhh1f = (const float*)d_in[15];
    const float* Wih1b = (const float*)d_in[16], *Whh1b = (const float*)d_in[17];
    const float* bih1b = (const float*)d_in[18], *bhh1b = (const float*)d_in[19];
    const float* out_w = (const float*)d_in[20];
    const float* out_b = (const float*)d_in[21];
    const float* trans = (const float*)d_in[22];

    char* ws = (char*)d_ws;
    size_t off = 0;
    auto alloc = [&](size_t bytes) -> void* {
        off = (off + 255) & ~(size_t)255;
        void* p = ws + off;
        off += bytes;
        return p;
    };
    unsigned short* X0  = (unsigned short*)alloc((size_t)MROWS * K0PAD * 2);
    unsigned short* dW0 = (unsigned short*)alloc((size_t)2 * 1024 * K0PAD * 2);
    unsigned short* dW1 = (unsigned short*)alloc((size_t)2 * 1024 * 512 * 2);
    unsigned short* dOW = (unsigned short*)alloc((size_t)64 * 512 * 2);
    unsigned int*   WQ  = (unsigned int*)alloc((size_t)4 * 131072 * 4);
    float*          bias= (float*)alloc((size_t)4096 * 4);
    int*            lens= (int*)alloc((size_t)32 * 4);
    float*          Gin = (float*)alloc((size_t)2 * MROWS * GATES * 4);
    unsigned short* H0  = (unsigned short*)alloc((size_t)MROWS * 512 * 2);
    unsigned short* H1  = (unsigned short*)alloc((size_t)MROWS * 512 * 2);
    float*          Y   = (float*)alloc((size_t)MROWS * Kv * 4);
    (void)ws_size; (void)in_sizes; (void)n_in; (void)out_size;

    // prep
    conv_weights<<<dim3(2048, 1, 5), 256, 0, stream>>>(Wih0f, Wih0b, Wih1f, Wih1b, out_w,
                                                       dW0, dW1, dOW);
    pack_whh<<<dim3(512, 1, 4), 256, 0, stream>>>(Whh0f, Whh0b, Whh1f, Whh1b, WQ);
    bias_sum<<<16, 256, 0, stream>>>(bih0f, bhh0f, bih0b, bhh0b,
                                     bih1f, bhh1f, bih1b, bhh1b, bias);
    calc_len<<<32, 256, 0, stream>>>(x, lens);
    embed_pack<<<MROWS, 64, 0, stream>>>(x, f, embed, X0);

    // layer 0
    mfma_gemm<<<dim3(MROWS / 32, 32), 64, 0, stream>>>(X0, K0PAD, dW0, K0PAD,
                                                       bias, Gin, GATES, K0PAD);
    mfma_gemm<<<dim3(MROWS / 32, 32), 64, 0, stream>>>(X0, K0PAD, dW0 + 1024 * K0PAD, K0PAD,
                                                       bias + 1024, Gin + (size_t)MROWS * GATES,
                                                       GATES, K0PAD);
    lstm_kernel<<<dim3(32, 2), 1024, 0, stream>>>(Gin, WQ, H0, lens);

    // layer 1
    mfma_gemm<<<dim3(MROWS / 32, 32), 64, 0, stream>>>(H0, 512, dW1, 512,
                                                       bias + 2048, Gin, GATES, 512);
    mfma_gemm<<<dim3(MROWS / 32, 32), 64, 0, stream>>>(H0, 512, dW1 + 1024 * 512, 512,
                                                       bias + 3072, Gin + (size_t)MROWS * GATES,
                                                       GATES, 512);
    lstm_kernel<<<dim3(32, 2), 1024, 0, stream>>>(Gin, WQ + 2 * 131072, H1, lens);

    // emissions + CRF
    mfma_gemm<<<dim3(MROWS / 32, 2), 64, 0, stream>>>(H1, 512, dOW, 512,
                                                      out_b, Y, Kv, 512);
    crf_kernel<<<32, 64, 0, stream>>>(Y, trans, y0, lens, (float*)d_out);
}

// Round 2
// 2585.228 us; speedup vs baseline: 1.1829x; 1.1829x over previous
//
#include <hip/hip_runtime.h>
#include <hip/hip_bf16.h>

// ---------------------------------------------------------------------------
// LSTM-CRF forward on MI355X.
// R2: slice-parallel LSTM. Whh is LDS-resident per (dir, j-slice) block;
// h(t) exchanged through a step-indexed global buffer with per-(step,slice)
// release/acquire flags (device scope, cross-XCD safe). Weights never
// re-stream from L2 (was the R1 bottleneck: 512 KB/step/CU).
// ---------------------------------------------------------------------------

#define Bv 32
#define Tv 256
#define Ev 300
#define HDv 256
#define Kv 64
#define MROWS (Bv * Tv)          // 8192
#define K0PAD 320                // 301 padded to mult of 32
#define GATES 1024               // 4*HD
#define NSLICE 16                // j-slices per dir
#define JS 16                    // j per slice
#define WFRAG_PER_DS (4 * 8 * 64 * 8)   // shorts per (dir,slice) weight block

typedef __bf16 v8bf __attribute__((ext_vector_type(8)));
typedef float  v4f  __attribute__((ext_vector_type(4)));

__device__ __forceinline__ unsigned short f2bf(float f) {
    unsigned u = __float_as_uint(f);
    unsigned r = (u + 0x7fffu + ((u >> 16) & 1u)) >> 16;
    return (unsigned short)r;
}
__device__ __forceinline__ float sigf(float x) { return 1.0f / (1.0f + __expf(-x)); }
__device__ __forceinline__ float tanhf2(float x) {
    x = fminf(15.f, fmaxf(-15.f, x));
    float e = __expf(2.f * x);
    return (e - 1.f) / (e + 1.f);
}

// ---------------- prep kernels ----------------

// z=0: Wih_l0f [1024,301]->[1024,320]  z=1: Wih_l0b
// z=2: Wih_l1f [1024,512]             z=3: Wih_l1b   z=4: out_w [64,512]
__global__ void conv_weights(const float* w0f, const float* w0b,
                             const float* w1f, const float* w1b,
                             const float* outw,
                             unsigned short* dW0, unsigned short* dW1,
                             unsigned short* dOW) {
    int z = blockIdx.z;
    const float* src; unsigned short* dst; int rows, kin, kout;
    if (z == 0)      { src = w0f;  dst = dW0;                rows = 1024; kin = 301; kout = K0PAD; }
    else if (z == 1) { src = w0b;  dst = dW0 + 1024 * K0PAD; rows = 1024; kin = 301; kout = K0PAD; }
    else if (z == 2) { src = w1f;  dst = dW1;                rows = 1024; kin = 512; kout = 512; }
    else if (z == 3) { src = w1b;  dst = dW1 + 1024 * 512;   rows = 1024; kin = 512; kout = 512; }
    else             { src = outw; dst = dOW;                rows = 64;   kin = 512; kout = 512; }
    int idx = blockIdx.x * 256 + threadIdx.x;
    if (idx >= rows * kout) return;
    int j = idx / kout, k = idx - j * kout;
    dst[idx] = (k < kin) ? f2bf(src[j * kin + k]) : (unsigned short)0;
}

// Whh [1024,256] fp32 -> bf16 MFMA B-fragment order:
// per (layer*2+dir) z: [slice(16)][gate(4)][kt(8)][lane(64)][e(8)]
// value = Whh[gate*256 + slice*16 + (lane&15)][kt*32 + (lane>>4)*8 + e]
__global__ void whh_frag(const float* h0f, const float* h0b,
                         const float* h1f, const float* h1b, unsigned short* Wfrag) {
    int z = blockIdx.z;
    const float* src = (z == 0) ? h0f : (z == 1) ? h0b : (z == 2) ? h1f : h1b;
    unsigned short* dst = Wfrag + (size_t)z * (NSLICE * WFRAG_PER_DS);
    int idx = blockIdx.x * 256 + threadIdx.x;          // 0..262143
    int e = idx & 7, ln = (idx >> 3) & 63, kt = (idx >> 9) & 7;
    int g = (idx >> 12) & 3, sl = idx >> 14;
    int n = g * 256 + sl * JS + (ln & 15);
    int k = kt * 32 + (ln >> 4) * 8 + e;
    dst[idx] = f2bf(src[n * 256 + k]);
}

__global__ void bias_sum(const float* a0, const float* b0, const float* a1, const float* b1,
                         const float* a2, const float* b2, const float* a3, const float* b3,
                         float* bias) {
    int idx = blockIdx.x * 256 + threadIdx.x;      // 0..4095
    int dl = idx >> 10, j = idx & 1023;
    const float* A = (dl == 0) ? a0 : (dl == 1) ? a1 : (dl == 2) ? a2 : a3;
    const float* B = (dl == 0) ? b0 : (dl == 1) ? b1 : (dl == 2) ? b2 : b3;
    bias[idx] = A[j] + B[j];
}

__global__ void calc_len(const int* x, int* lengths) {
    __shared__ int cnt;
    if (threadIdx.x == 0) cnt = 0;
    __syncthreads();
    if (x[blockIdx.x * Tv + threadIdx.x] > 0) atomicAdd(&cnt, 1);
    __syncthreads();
    if (threadIdx.x == 0) lengths[blockIdx.x] = cnt;
}

__global__ void zero_flags(int* flags) {
    flags[blockIdx.x * 256 + threadIdx.x] = 0;
}

// X0 row = [embed[tok](300) | f(1) | zeros(19)] as bf16
__global__ void embed_pack(const int* __restrict__ x, const float* __restrict__ f,
                           const float* __restrict__ embed, unsigned short* __restrict__ X0) {
    int row = blockIdx.x;
    int tok = x[row];
    float fv = f[row];
    const float* e = embed + (size_t)tok * Ev;
    for (int k = threadIdx.x; k < K0PAD; k += 64) {
        float v = (k < Ev) ? e[k] : ((k == Ev) ? fv : 0.f);
        X0[(size_t)row * K0PAD + k] = f2bf(v);
    }
}

// ---------------- MFMA GEMM: C[M,N] = X[M,K] @ W[N,K]^T + bias[N] ----------
__global__ __launch_bounds__(64) void mfma_gemm(
    const unsigned short* __restrict__ X, int ldx,
    const unsigned short* __restrict__ W, int ldw,
    const float* __restrict__ bias, float* __restrict__ C, int ldc, int K) {
    int lane = threadIdx.x;
    int m0 = blockIdx.x * 32, n0 = blockIdx.y * 32;
    int r = lane & 15, q = lane >> 4;
    const unsigned short* xa = X + (size_t)(m0 + r) * ldx + q * 8;
    const unsigned short* xb = xa + (size_t)16 * ldx;
    const unsigned short* wa = W + (size_t)(n0 + r) * ldw + q * 8;
    const unsigned short* wb = wa + (size_t)16 * ldw;
    v4f acc00 = {0.f, 0.f, 0.f, 0.f};
    v4f acc01 = acc00, acc10 = acc00, acc11 = acc00;
#pragma unroll 4
    for (int k = 0; k < K; k += 32) {
        v8bf a0 = *(const v8bf*)(xa + k);
        v8bf a1 = *(const v8bf*)(xb + k);
        v8bf b0 = *(const v8bf*)(wa + k);
        v8bf b1 = *(const v8bf*)(wb + k);
        acc00 = __builtin_amdgcn_mfma_f32_16x16x32_bf16(a0, b0, acc00, 0, 0, 0);
        acc01 = __builtin_amdgcn_mfma_f32_16x16x32_bf16(a0, b1, acc01, 0, 0, 0);
        acc10 = __builtin_amdgcn_mfma_f32_16x16x32_bf16(a1, b0, acc10, 0, 0, 0);
        acc11 = __builtin_amdgcn_mfma_f32_16x16x32_bf16(a1, b1, acc11, 0, 0, 0);
    }
    int col = n0 + r;
    float bv0 = bias[col], bv1 = bias[col + 16];
#pragma unroll
    for (int i = 0; i < 4; ++i) {
        int row = m0 + q * 4 + i;
        C[(size_t)row * ldc + col]             = acc00[i] + bv0;
        C[(size_t)row * ldc + col + 16]        = acc01[i] + bv1;
        C[(size_t)(row + 16) * ldc + col]      = acc10[i] + bv0;
        C[(size_t)(row + 16) * ldc + col + 16] = acc11[i] + bv1;
    }
}

// ---------------- slice-parallel LSTM ----------------
// grid (NSLICE, 2 dirs), block 256 (wave g = gate g). Per layer launch.
// Gin [2][8192][1024] fp32 (input GEMM + bias), Wfrag: this layer's fragment
// weights, Hstate [2][256 steps][32][256] bf16 (state history, step-indexed),
// Hout [8192][512] bf16 (masked layer output), flags: this layer [2][256][16].
__global__ __launch_bounds__(256) void lstm_slice(
    const float* __restrict__ Gin,
    const unsigned short* __restrict__ Wfrag,
    unsigned short* __restrict__ Hstate,
    unsigned short* __restrict__ Hout,
    int* __restrict__ flags,
    const int* __restrict__ lengths) {
    const int d = blockIdx.y, sl = blockIdx.x;
    const int tid = threadIdx.x;
    const int lane = tid & 63, g = tid >> 6;
    const int j0 = sl * JS;

    __shared__ __align__(16) unsigned short A[32][264];       // h(t-1), padded rows (528B)
    __shared__ __align__(16) unsigned short W[4][8][64][8];   // 32 KB B-fragments
    __shared__ float GT[4][32][17];                           // gate staging (+pad)

    // stage weights once: 32 KB contiguous
    {
        const uint4* src = (const uint4*)(Wfrag + (size_t)(d * NSLICE + sl) * WFRAG_PER_DS);
        uint4* dst = (uint4*)(&W[0][0][0][0]);
        for (int i = tid; i < 2048; i += 256) dst[i] = src[i];
    }
    const int jj = tid & 15;
    const int b0 = tid >> 4, b1 = 16 + (tid >> 4);
    const int len0 = lengths[b0], len1 = lengths[b1];
    float c0 = 0.f, h0 = 0.f, c1 = 0.f, h1 = 0.f;
    int* myflags = flags + d * (256 * NSLICE);
    unsigned short* Hst = Hstate + (size_t)d * 256 * Bv * HDv;
    const float* gin_d = Gin + (size_t)d * MROWS * GATES;
    const int ar = lane & 15, aq = lane >> 4;
    __syncthreads();

    for (int s = 0; s < 256; ++s) {
        const int t = d ? 255 - s : s;
        // prefetch Gin (independent of flags; issued before polling)
        float gv0[4], gv1[4];
        const float* gp0 = gin_d + ((size_t)b0 * Tv + t) * GATES + j0 + jj;
        const float* gp1 = gin_d + ((size_t)b1 * Tv + t) * GATES + j0 + jj;
#pragma unroll
        for (int q = 0; q < 4; ++q) { gv0[q] = gp0[q * 256]; gv1[q] = gp1[q * 256]; }

        if (s > 0) {
            // each wave: lanes<16 poll the 16 slice flags of step s-1
            if (lane < 16) {
                const int* fp = myflags + (s - 1) * NSLICE + lane;
                int spins = 0;
                while (__hip_atomic_load(fp, __ATOMIC_RELAXED, __HIP_MEMORY_SCOPE_AGENT) == 0) {
                    __builtin_amdgcn_s_sleep(8);
                    if (++spins > (1 << 25)) break;   // safety: terminate, don't hang
                }
                (void)__hip_atomic_load(fp, __ATOMIC_ACQUIRE, __HIP_MEMORY_SCOPE_AGENT);
            }
            // cooperative load A = Hstate[d][s-1] (16 KB, coalesced)
            {
                const uint4* hs = (const uint4*)(Hst + (size_t)(s - 1) * Bv * HDv);
                int brow = tid >> 3, c8 = tid & 7;
                const uint4* srcp = hs + brow * 32 + c8 * 4;
#pragma unroll
                for (int i = 0; i < 4; ++i)
                    *(uint4*)(&A[brow][c8 * 32 + i * 8]) = srcp[i];
            }
            __syncthreads();
            // wave g: gates[g] slice = A[32,256] @ W[g][16,256]^T
            v4f acc0 = {0.f, 0.f, 0.f, 0.f}, acc1 = acc0;
#pragma unroll
            for (int kt = 0; kt < 8; ++kt) {
                v8bf bfr = *(const v8bf*)(&W[g][kt][lane][0]);
                v8bf a0  = *(const v8bf*)(&A[ar][kt * 32 + aq * 8]);
                v8bf a1  = *(const v8bf*)(&A[16 + ar][kt * 32 + aq * 8]);
                acc0 = __builtin_amdgcn_mfma_f32_16x16x32_bf16(a0, bfr, acc0, 0, 0, 0);
                acc1 = __builtin_amdgcn_mfma_f32_16x16x32_bf16(a1, bfr, acc1, 0, 0, 0);
            }
#pragma unroll
            for (int r = 0; r < 4; ++r) {          // C: col=lane&15 (j), row=quad*4+r (b)
                GT[g][aq * 4 + r][ar]      = acc0[r];
                GT[g][16 + aq * 4 + r][ar] = acc1[r];
            }
            __syncthreads();
        } else {
            __syncthreads();
        }
        // update: thread owns (b0,jj) and (b1,jj); c/h state in registers
        {
            float p0[4], p1[4];
#pragma unroll
            for (int q = 0; q < 4; ++q) {
                p0[q] = gv0[q] + (s > 0 ? GT[q][b0][jj] : 0.f);
                p1[q] = gv1[q] + (s > 0 ? GT[q][b1][jj] : 0.f);
            }
            {
                float ig = sigf(p0[0]), fg = sigf(p0[1]);
                float gg = tanhf2(p0[2]), og = sigf(p0[3]);
                float cn = fg * c0 + ig * gg;
                float hn = og * tanhf2(cn);
                bool m = (t < len0);
                c0 = m ? cn : c0; h0 = m ? hn : h0;
                Hst[(size_t)s * Bv * HDv + b0 * HDv + j0 + jj] = f2bf(h0);
                Hout[((size_t)b0 * Tv + t) * 512 + d * HDv + j0 + jj] =
                    m ? f2bf(hn) : (unsigned short)0;
            }
            {
                float ig = sigf(p1[0]), fg = sigf(p1[1]);
                float gg = tanhf2(p1[2]), og = sigf(p1[3]);
                float cn = fg * c1 + ig * gg;
                float hn = og * tanhf2(cn);
                bool m = (t < len1);
                c1 = m ? cn : c1; h1 = m ? hn : h1;
                Hst[(size_t)s * Bv * HDv + b1 * HDv + j0 + jj] = f2bf(h1);
                Hout[((size_t)b1 * Tv + t) * 512 + d * HDv + j0 + jj] =
                    m ? f2bf(hn) : (unsigned short)0;
            }
        }
        __syncthreads();   // implies vmcnt(0): all stores issued to L2
        if (tid == 0)
            __hip_atomic_store(myflags + s * NSLICE + sl, 1,
                               __ATOMIC_RELEASE, __HIP_MEMORY_SCOPE_AGENT);
    }
}

// ---------------- CRF ----------------
__global__ __launch_bounds__(64) void crf_kernel(
    const float* __restrict__ Y, const float* __restrict__ trans,
    const int* __restrict__ y0, const int* __restrict__ lengths,
    float* __restrict__ out) {
    int b = blockIdx.x, j = threadIdx.x;
    int len = lengths[b];
    float trj[64];
#pragma unroll
    for (int i = 0; i < 64; ++i) trj[i] = trans[j * 64 + i];
    __shared__ __align__(16) float s[64];
    s[j] = (j == 2) ? 0.f : -10000.f;
    __syncthreads();
    const float* yb = Y + (size_t)b * Tv * Kv;
    for (int t = 0; t < len; ++t) {
        float emit = yb[t * 64 + j];
        float m = -3.0e38f;
#pragma unroll
        for (int i = 0; i < 64; ++i) m = fmaxf(m, s[i] + trj[i]);
        float sum = 0.f;
#pragma unroll
        for (int i = 0; i < 64; ++i) sum += __expf(s[i] + trj[i] - m);
        float ns = m + __logf(sum) + emit;
        __syncthreads();
        s[j] = ns;
        __syncthreads();
    }
    float v = s[j];
    float M = v;
#pragma unroll
    for (int o = 32; o; o >>= 1) M = fmaxf(M, __shfl_xor(M, o));
    float e = __expf(v - M);
#pragma unroll
    for (int o = 32; o; o >>= 1) e += __shfl_xor(e, o);
    float Z = M + __logf(e);
    float gold = 0.f;
    for (int t = j; t < len; t += 64) {
        int yt = y0[b * Tv + t];
        int yp = (t == 0) ? 2 : y0[b * Tv + t - 1];
        gold += yb[t * 64 + yt] + trans[yt * 64 + yp];
    }
#pragma unroll
    for (int o = 32; o; o >>= 1) gold += __shfl_xor(gold, o);
    if (j == 0) out[b] = Z - gold;
}

// ---------------- host ----------------
extern "C" void kernel_launch(void* const* d_in, const int* in_sizes, int n_in,
                              void* d_out, int out_size, void* d_ws, size_t ws_size,
                              hipStream_t stream) {
    const int*   x     = (const int*)d_in[0];
    const float* f     = (const float*)d_in[1];
    const int*   y0    = (const int*)d_in[2];
    const float* embed = (const float*)d_in[3];
    const float* Wih0f = (const float*)d_in[4],  *Whh0f = (const float*)d_in[5];
    const float* bih0f = (const float*)d_in[6],  *bhh0f = (const float*)d_in[7];
    const float* Wih0b = (const float*)d_in[8],  *Whh0b = (const float*)d_in[9];
    const float* bih0b = (const float*)d_in[10], *bhh0b = (const float*)d_in[11];
    const float* Wih1f = (const float*)d_in[12], *Whh1f = (const float*)d_in[13];
    const float* bih1f = (const float*)d_in[14], *bhh1f = (const float*)d_in[15];
    const float* Wih1b = (const float*)d_in[16], *Whh1b = (const float*)d_in[17];
    const float* bih1b = (const float*)d_in[18], *bhh1b = (const float*)d_in[19];
    const float* out_w = (const float*)d_in[20];
    const float* out_b = (const float*)d_in[21];
    const float* trans = (const float*)d_in[22];

    char* ws = (char*)d_ws;
    size_t off = 0;
    auto alloc = [&](size_t bytes) -> void* {
        off = (off + 255) & ~(size_t)255;
        void* p = ws + off;
        off += bytes;
        return p;
    };
    unsigned short* X0   = (unsigned short*)alloc((size_t)MROWS * K0PAD * 2);
    unsigned short* dW0  = (unsigned short*)alloc((size_t)2 * 1024 * K0PAD * 2);
    unsigned short* dW1  = (unsigned short*)alloc((size_t)2 * 1024 * 512 * 2);
    unsigned short* dOW  = (unsigned short*)alloc((size_t)64 * 512 * 2);
    unsigned short* Wfrag= (unsigned short*)alloc((size_t)4 * NSLICE * WFRAG_PER_DS * 2);
    float*          bias = (float*)alloc((size_t)4096 * 4);
    int*            lens = (int*)alloc((size_t)32 * 4);
    int*            flags= (int*)alloc((size_t)2 * 2 * 256 * NSLICE * 4);
    unsigned short* Hstate=(unsigned short*)alloc((size_t)2 * 256 * Bv * HDv * 2);
    float*          Gin  = (float*)alloc((size_t)2 * MROWS * GATES * 4);
    unsigned short* H0   = (unsigned short*)alloc((size_t)MROWS * 512 * 2);
    unsigned short* H1   = (unsigned short*)alloc((size_t)MROWS * 512 * 2);
    float*          Y    = (float*)alloc((size_t)MROWS * Kv * 4);
    (void)ws_size; (void)in_sizes; (void)n_in; (void)out_size;

    // prep
    conv_weights<<<dim3(2048, 1, 5), 256, 0, stream>>>(Wih0f, Wih0b, Wih1f, Wih1b, out_w,
                                                       dW0, dW1, dOW);
    whh_frag<<<dim3(1024, 1, 4), 256, 0, stream>>>(Whh0f, Whh0b, Whh1f, Whh1b, Wfrag);
    bias_sum<<<16, 256, 0, stream>>>(bih0f, bhh0f, bih0b, bhh0b,
                                     bih1f, bhh1f, bih1b, bhh1b, bias);
    calc_len<<<32, 256, 0, stream>>>(x, lens);
    zero_flags<<<64, 256, 0, stream>>>(flags);
    embed_pack<<<MROWS, 64, 0, stream>>>(x, f, embed, X0);

    // layer 0
    mfma_gemm<<<dim3(MROWS / 32, 32), 64, 0, stream>>>(X0, K0PAD, dW0, K0PAD,
                                                       bias, Gin, GATES, K0PAD);
    mfma_gemm<<<dim3(MROWS / 32, 32), 64, 0, stream>>>(X0, K0PAD, dW0 + 1024 * K0PAD, K0PAD,
                                                       bias + 1024, Gin + (size_t)MROWS * GATES,
                                                       GATES, K0PAD);
    lstm_slice<<<dim3(NSLICE, 2), 256, 0, stream>>>(Gin, Wfrag, Hstate, H0, flags, lens);

    // layer 1
    mfma_gemm<<<dim3(MROWS / 32, 32), 64, 0, stream>>>(H0, 512, dW1, 512,
                                                       bias + 2048, Gin, GATES, 512);
    mfma_gemm<<<dim3(MROWS / 32, 32), 64, 0, stream>>>(H0, 512, dW1 + 1024 * 512, 512,
                                                       bias + 3072, Gin + (size_t)MROWS * GATES,
                                                       GATES, 512);
    lstm_slice<<<dim3(NSLICE, 2), 256, 0, stream>>>(Gin, Wfrag + (size_t)2 * NSLICE * WFRAG_PER_DS,
                                                    Hstate, H1, flags + 2 * 256 * NSLICE, lens);

    // emissions + CRF
    mfma_gemm<<<dim3(MROWS / 32, 2), 64, 0, stream>>>(H1, 512, dOW, 512,
                                                      out_b, Y, Kv, 512);
    crf_kernel<<<32, 64, 0, stream>>>(Y, trans, y0, lens, (float*)d_out);
}